// Round 4
// baseline (36.849 us; speedup 1.0000x reference)
//
#include <hip/hip_runtime.h>

#define BATCH 384
#define DIM   1024
#define MARGIN_F 0.5f
#define EPS_F 1e-16f
#define N2 (BATCH * BATCH)

// ---------------------------------------------------------------------------
// Kernel 1: split-K partial gram matrix, 64x64 tile / block, 4x4 micro-tile.
// dot_z[i][j] = sum_{k in slice z} E[i][k]*E[j][k]
// Per 4-k step: 8 ds_read_b128 + 64 FMA per thread -> FMA-bound (was
// LDS-read-bound with the 2x2 micro-tile). Diagonal blocks write dot_ii
// partials to ddiag (exact-0 diagonal reconstruction in the consumer).
// No atomics, no counters - plain 3-kernel pipeline (round-2 structure).
// ---------------------------------------------------------------------------
__global__ __launch_bounds__(256) void dist_kernel(const float* __restrict__ E,
                                                   float* __restrict__ dpart,
                                                   float* __restrict__ ddiag,
                                                   int kslice) {
    __shared__ float As[64][36];
    __shared__ float Bs[64][36];

    const int tx = threadIdx.x & 15;   // cols tx + 16n, n=0..3
    const int ty = threadIdx.x >> 4;   // rows ty + 16m, m=0..3
    const int rb = blockIdx.y * 64;
    const int cb = blockIdx.x * 64;
    const int kb = blockIdx.z * kslice;

    float acc[4][4];
#pragma unroll
    for (int m = 0; m < 4; ++m)
#pragma unroll
        for (int n = 0; n < 4; ++n) acc[m][n] = 0.f;

    const int lr = threadIdx.x >> 3;        // 0..31
    const int lc = (threadIdx.x & 7) * 4;   // 0,4,...,28

    for (int k0 = 0; k0 < kslice; k0 += 32) {
        // stage 64 rows x 32 k of A and B: 2 float4 per thread per array
        *(float4*)&As[lr][lc]      = *(const float4*)&E[(size_t)(rb + lr) * DIM + kb + k0 + lc];
        *(float4*)&As[lr + 32][lc] = *(const float4*)&E[(size_t)(rb + lr + 32) * DIM + kb + k0 + lc];
        *(float4*)&Bs[lr][lc]      = *(const float4*)&E[(size_t)(cb + lr) * DIM + kb + k0 + lc];
        *(float4*)&Bs[lr + 32][lc] = *(const float4*)&E[(size_t)(cb + lr + 32) * DIM + kb + k0 + lc];
        __syncthreads();

#pragma unroll
        for (int k = 0; k < 32; k += 4) {
            float4 a[4], b[4];
#pragma unroll
            for (int m = 0; m < 4; ++m) a[m] = *(const float4*)&As[ty + 16 * m][k];
#pragma unroll
            for (int n = 0; n < 4; ++n) b[n] = *(const float4*)&Bs[tx + 16 * n][k];
#pragma unroll
            for (int m = 0; m < 4; ++m)
#pragma unroll
                for (int n = 0; n < 4; ++n)
                    acc[m][n] += a[m].x * b[n].x + a[m].y * b[n].y +
                                 a[m].z * b[n].z + a[m].w * b[n].w;
        }
        __syncthreads();
    }

    float* dst = dpart + (size_t)blockIdx.z * N2;
#pragma unroll
    for (int m = 0; m < 4; ++m) {
        const int r = rb + ty + 16 * m;
#pragma unroll
        for (int n = 0; n < 4; ++n)
            dst[(size_t)r * BATCH + cb + tx + 16 * n] = acc[m][n];
    }

    if (blockIdx.x == blockIdx.y && tx == ty) {
#pragma unroll
        for (int m = 0; m < 4; ++m)
            ddiag[blockIdx.z * BATCH + rb + ty + 16 * m] = acc[m][m];
    }
}

// ---------------------------------------------------------------------------
// Kernel 2: per-anchor triplet reduction (round-2 structure: partials only).
// drow[i] = sqrt(da + di - 2*dot_ai); exactly 0.0 at i==a.
// ---------------------------------------------------------------------------
__global__ __launch_bounds__(256) void triplet_kernel(const float* __restrict__ dpart,
                                                      const float* __restrict__ ddiag,
                                                      const int* __restrict__ labels,
                                                      float* __restrict__ part,
                                                      int nslice) {
    __shared__ float drow[BATCH];
    __shared__ int   lab[BATCH];
    __shared__ int   plist[BATCH];
    __shared__ int   npos_s;
    __shared__ float ssum[4];
    __shared__ int   spos[4];
    __shared__ int   sval[4];

    const int t = threadIdx.x;
    const int a = blockIdx.x;

    float da = 0.f;
    for (int z = 0; z < nslice; ++z) da += ddiag[z * BATCH + a];

    for (int i = t; i < BATCH; i += 256) {
        float row = 0.f, di = 0.f;
        for (int z = 0; z < nslice; ++z) {
            row += dpart[(size_t)z * N2 + (size_t)a * BATCH + i];
            di  += ddiag[z * BATCH + i];
        }
        const float s = da + di - 2.f * row;   // exactly 0.0 at i==a
        drow[i] = s > 0.f ? sqrtf(s) : 0.f;
        lab[i]  = labels[i];
    }
    __syncthreads();

    const int la = lab[a];

    // deterministic positives-list build on wave 0
    if (t < 64) {
        int cnt = 0;
#pragma unroll
        for (int c = 0; c < BATCH; c += 64) {
            const int i = c + t;
            const bool f = (lab[i] == la) && (i != a);
            const unsigned long long m = __ballot(f);
            if (f) {
                const int off = __popcll(m & ((1ull << t) - 1ull));
                plist[cnt + off] = i;
            }
            cnt += __popcll(m);
        }
        if (t == 0) npos_s = cnt;
    }
    __syncthreads();

    const int npos = npos_s;
    float sum = 0.f;
    int   pos = 0, valid = 0;

    for (int n = t; n < BATCH; n += 256) {
        if (lab[n] != la) {
            const float dan = drow[n];
            valid += npos;
            for (int q = 0; q < npos; ++q) {
                float tl = drow[plist[q]] - dan + MARGIN_F;
                if (tl > EPS_F) { sum += tl; ++pos; }
            }
        }
    }

#pragma unroll
    for (int off = 32; off > 0; off >>= 1) {
        sum   += __shfl_down(sum, off);
        pos   += __shfl_down(pos, off);
        valid += __shfl_down(valid, off);
    }
    const int wave = t >> 6, lane = t & 63;
    if (lane == 0) { ssum[wave] = sum; spos[wave] = pos; sval[wave] = valid; }
    __syncthreads();

    if (t == 0) {
        float s = 0.f; int p2 = 0, v = 0;
#pragma unroll
        for (int w = 0; w < 4; ++w) { s += ssum[w]; p2 += spos[w]; v += sval[w]; }
        part[a]             = s;
        part[BATCH + a]     = (float)p2;
        part[2 * BATCH + a] = (float)v;
    }
}

// ---------------------------------------------------------------------------
// Kernel 3: one-wave finalize. Double accumulation of 384 partials.
// ---------------------------------------------------------------------------
__global__ __launch_bounds__(64) void finalize_kernel(const float* __restrict__ part,
                                                      float* __restrict__ out) {
    const int lane = threadIdx.x;
    double s = 0.0, p = 0.0, v = 0.0;
#pragma unroll
    for (int c = 0; c < BATCH; c += 64) {
        s += (double)part[c + lane];
        p += (double)part[BATCH + c + lane];
        v += (double)part[2 * BATCH + c + lane];
    }
#pragma unroll
    for (int off = 32; off > 0; off >>= 1) {
        s += __shfl_down(s, off);
        p += __shfl_down(p, off);
        v += __shfl_down(v, off);
    }
    if (lane == 0) {
        out[0] = (float)(s / (p + 1e-16));
        out[1] = (float)p;
        out[2] = (float)v;
    }
}

extern "C" void kernel_launch(void* const* d_in, const int* in_sizes, int n_in,
                              void* d_out, int out_size, void* d_ws, size_t ws_size,
                              hipStream_t stream) {
    const int*   labels = (const int*)d_in[0];
    const float* E      = (const float*)d_in[1];
    float* out = (float*)d_out;

    // ws layout: [part @0: 3*384 f][ddiag @8192: S*384 f][dpart @65536: S*N2 f]
    float* part  = (float*)d_ws;
    float* ddiag = (float*)((char*)d_ws + 8192);
    float* dpart = (float*)((char*)d_ws + 65536);

    int S = 16;
    while (S > 1 && 65536 + (size_t)S * N2 * sizeof(float) > ws_size) S >>= 1;
    const int kslice = DIM / S;

    dim3 grid(BATCH / 64, BATCH / 64, S);
    dist_kernel<<<grid, 256, 0, stream>>>(E, dpart, ddiag, kslice);
    triplet_kernel<<<BATCH, 256, 0, stream>>>(dpart, ddiag, labels, part, S);
    finalize_kernel<<<1, 64, 0, stream>>>(part, out);
}

// Round 5
// 24.721 us; speedup vs baseline: 1.4906x; 1.4906x over previous
//
#include <hip/hip_runtime.h>

#define BATCH 384
#define DIM   1024
#define MARGIN_F 0.5f
#define EPS_F 1e-16f
#define N2 (BATCH * BATCH)

// ---------------------------------------------------------------------------
// Kernel 1: split-K partial squared distances, UPPER-TRIANGLE tiles only.
// Block (bx,by,bz) with bx>=by computes the 32x32 tile (by,bx) of
// sum_{k in slice bz} (E[i][k]-E[j][k])^2 and mirror-stores the transpose
// ((a-b)^2 == (b-a)^2 bitwise, same k order -> exact symmetry).
// Lower-triangle blocks exit immediately. Diff form keeps the diagonal
// exactly 0. 2x2 micro-tile, [32][33] LDS (round-2 proven inner loop).
// ---------------------------------------------------------------------------
__global__ __launch_bounds__(256) void dist_kernel(const float* __restrict__ E,
                                                   float* __restrict__ dpart,
                                                   int kslice) {
    const int bx = blockIdx.x, by = blockIdx.y;
    if (bx < by) return;   // triangle: only cb >= rb tiles do work

    __shared__ float As[32][33];
    __shared__ float Bs[32][33];

    const int tx = threadIdx.x & 15;
    const int ty = threadIdx.x >> 4;
    const int rb = by * 32;
    const int cb = bx * 32;
    const int kb = blockIdx.z * kslice;

    float acc00 = 0.f, acc01 = 0.f, acc10 = 0.f, acc11 = 0.f;

    const int lr = threadIdx.x >> 3;        // 0..31 row within tile
    const int lc = (threadIdx.x & 7) * 4;   // 0,4,...,28

    for (int k0 = 0; k0 < kslice; k0 += 32) {
        float4 av = *(const float4*)&E[(size_t)(rb + lr) * DIM + kb + k0 + lc];
        float4 bv = *(const float4*)&E[(size_t)(cb + lr) * DIM + kb + k0 + lc];
        As[lr][lc + 0] = av.x; As[lr][lc + 1] = av.y;
        As[lr][lc + 2] = av.z; As[lr][lc + 3] = av.w;
        Bs[lr][lc + 0] = bv.x; Bs[lr][lc + 1] = bv.y;
        Bs[lr][lc + 2] = bv.z; Bs[lr][lc + 3] = bv.w;
        __syncthreads();

#pragma unroll
        for (int k = 0; k < 32; ++k) {
            float a0 = As[ty * 2 + 0][k];
            float a1 = As[ty * 2 + 1][k];
            float b0 = Bs[tx * 2 + 0][k];
            float b1 = Bs[tx * 2 + 1][k];
            float t;
            t = a0 - b0; acc00 += t * t;
            t = a0 - b1; acc01 += t * t;
            t = a1 - b0; acc10 += t * t;
            t = a1 - b1; acc11 += t * t;
        }
        __syncthreads();
    }

    float* dst = dpart + (size_t)blockIdx.z * N2;
    const int r0 = rb + ty * 2, c0 = cb + tx * 2;
    dst[(size_t)(r0 + 0) * BATCH + c0 + 0] = acc00;
    dst[(size_t)(r0 + 0) * BATCH + c0 + 1] = acc01;
    dst[(size_t)(r0 + 1) * BATCH + c0 + 0] = acc10;
    dst[(size_t)(r0 + 1) * BATCH + c0 + 1] = acc11;

    if (bx != by) {   // mirror store (transposed); bit-identical values
        dst[(size_t)(c0 + 0) * BATCH + r0 + 0] = acc00;
        dst[(size_t)(c0 + 1) * BATCH + r0 + 0] = acc01;
        dst[(size_t)(c0 + 0) * BATCH + r0 + 1] = acc10;
        dst[(size_t)(c0 + 1) * BATCH + r0 + 1] = acc11;
    }
}

// ---------------------------------------------------------------------------
// Kernel 2: per-anchor triplet reduction (round-2 structure), templated on
// slice count so the partial-sum z-loop fully unrolls (8 independent loads
// in flight instead of a serial latency chain; same add order -> bit-equal).
// ---------------------------------------------------------------------------
template <int NS>
__global__ __launch_bounds__(256) void triplet_kernel(const float* __restrict__ dpart,
                                                      const int* __restrict__ labels,
                                                      float* __restrict__ part) {
    __shared__ float drow[BATCH];
    __shared__ int   lab[BATCH];
    __shared__ int   plist[BATCH];
    __shared__ int   npos_s;
    __shared__ float ssum[4];
    __shared__ int   spos[4];
    __shared__ int   sval[4];

    const int t = threadIdx.x;
    const int a = blockIdx.x;

    for (int i = t; i < BATCH; i += 256) {
        float s = 0.f;
#pragma unroll
        for (int z = 0; z < NS; ++z)
            s += dpart[(size_t)z * N2 + (size_t)a * BATCH + i];
        drow[i] = s > 0.f ? sqrtf(s) : 0.f;
        lab[i]  = labels[i];
    }
    __syncthreads();

    const int la = lab[a];

    // deterministic positives-list build on wave 0
    if (t < 64) {
        int cnt = 0;
#pragma unroll
        for (int c = 0; c < BATCH; c += 64) {
            const int i = c + t;
            const bool f = (lab[i] == la) && (i != a);
            const unsigned long long m = __ballot(f);
            if (f) {
                const int off = __popcll(m & ((1ull << t) - 1ull));
                plist[cnt + off] = i;
            }
            cnt += __popcll(m);
        }
        if (t == 0) npos_s = cnt;
    }
    __syncthreads();

    const int npos = npos_s;
    float sum = 0.f;
    int   pos = 0, valid = 0;

    for (int n = t; n < BATCH; n += 256) {
        if (lab[n] != la) {
            const float dan = drow[n];
            valid += npos;
            for (int q = 0; q < npos; ++q) {
                float tl = drow[plist[q]] - dan + MARGIN_F;
                if (tl > EPS_F) { sum += tl; ++pos; }
            }
        }
    }

#pragma unroll
    for (int off = 32; off > 0; off >>= 1) {
        sum   += __shfl_down(sum, off);
        pos   += __shfl_down(pos, off);
        valid += __shfl_down(valid, off);
    }
    const int wave = t >> 6, lane = t & 63;
    if (lane == 0) { ssum[wave] = sum; spos[wave] = pos; sval[wave] = valid; }
    __syncthreads();

    if (t == 0) {
        float s = 0.f; int p2 = 0, v = 0;
#pragma unroll
        for (int w = 0; w < 4; ++w) { s += ssum[w]; p2 += spos[w]; v += sval[w]; }
        part[a]             = s;
        part[BATCH + a]     = (float)p2;
        part[2 * BATCH + a] = (float)v;
    }
}

// ---------------------------------------------------------------------------
// Kernel 3: one-wave finalize. Double accumulation of 384 partials.
// ---------------------------------------------------------------------------
__global__ __launch_bounds__(64) void finalize_kernel(const float* __restrict__ part,
                                                      float* __restrict__ out) {
    const int lane = threadIdx.x;
    double s = 0.0, p = 0.0, v = 0.0;
#pragma unroll
    for (int c = 0; c < BATCH; c += 64) {
        s += (double)part[c + lane];
        p += (double)part[BATCH + c + lane];
        v += (double)part[2 * BATCH + c + lane];
    }
#pragma unroll
    for (int off = 32; off > 0; off >>= 1) {
        s += __shfl_down(s, off);
        p += __shfl_down(p, off);
        v += __shfl_down(v, off);
    }
    if (lane == 0) {
        out[0] = (float)(s / (p + 1e-16));
        out[1] = (float)p;
        out[2] = (float)v;
    }
}

extern "C" void kernel_launch(void* const* d_in, const int* in_sizes, int n_in,
                              void* d_out, int out_size, void* d_ws, size_t ws_size,
                              hipStream_t stream) {
    const int*   labels = (const int*)d_in[0];
    const float* E      = (const float*)d_in[1];
    float* out = (float*)d_out;

    // workspace layout: [part: 3*384 floats, pad to 8KB][dpart: S * 384*384 floats]
    float* part  = (float*)d_ws;
    float* dpart = (float*)((char*)d_ws + 8192);

    int S = 8;
    while (S > 1 && 8192 + (size_t)S * N2 * sizeof(float) > ws_size) S >>= 1;
    const int kslice = DIM / S;

    dim3 grid(BATCH / 32, BATCH / 32, S);
    dist_kernel<<<grid, 256, 0, stream>>>(E, dpart, kslice);

    switch (S) {
        case 8: triplet_kernel<8><<<BATCH, 256, 0, stream>>>(dpart, labels, part); break;
        case 4: triplet_kernel<4><<<BATCH, 256, 0, stream>>>(dpart, labels, part); break;
        case 2: triplet_kernel<2><<<BATCH, 256, 0, stream>>>(dpart, labels, part); break;
        default: triplet_kernel<1><<<BATCH, 256, 0, stream>>>(dpart, labels, part); break;
    }
    finalize_kernel<<<1, 64, 0, stream>>>(part, out);
}